// Round 3
// baseline (4130.458 us; speedup 1.0000x reference)
//
#include <hip/hip_runtime.h>
#include <cstdint>
#include <cstddef>

// LayerNormLSTM on MI355X.
// Phase 0: fp32->bf16 conversion of x, Wi, Wh; tagged init of h(0).
// Phase 1: Gpre = x @ Wi^T  (bf16 MFMA 16x16x32, 128x128 tiles).
// Phase 1.5: in-place row LN (scale=b1, shift=s1) over the 2048 gate dim.
// Phase 2: persistent recurrence. R6: same-XCD teams + L2-scope (sc0) sync.
//   - 320 wgs launched; runtime team formation groups 16 co-located wgs
//     (same XCC_ID) into each of 4 teams; surplus wgs exit. One-time MALL
//     atomics; release/acquire on arrive counter; deadlock-free.
//   - All per-step rendezvous (tagged-u64 parity protocol, unchanged from
//     R5) now use sc0 (bypass L1, served by the shared per-XCD L2) loads.
//   - Every post is double-stored (sc0 + agent/MALL mirror, same value);
//     every poll has a sticky >64-spin fallback to MALL loads. Any wrong
//     assumption (XCC encoding, sc0 semantics, placement) degrades to the
//     proven R5 behavior instead of hanging.

typedef float  f32x4 __attribute__((ext_vector_type(4)));
typedef __bf16 bf16x8 __attribute__((ext_vector_type(8)));
typedef unsigned int u32x4 __attribute__((ext_vector_type(4)));
typedef unsigned short u16x4 __attribute__((ext_vector_type(4)));

#define DEV __device__ __forceinline__

#define LD2_SC0(dst, p) asm volatile("global_load_dwordx2 %0, %1, off sc0" : "=v"(dst) : "v"(p))
#define ST2_SC0(p, v)   asm volatile("global_store_dwordx2 %0, %1, off sc0" :: "v"(p), "v"(v) : "memory")
#define LD2_MALL(dst, p) (dst) = __hip_atomic_load((p), __ATOMIC_RELAXED, __HIP_MEMORY_SCOPE_AGENT)
#define VM0_FENCE() do{ asm volatile("s_waitcnt vmcnt(0)" ::: "memory"); \
                        __builtin_amdgcn_sched_barrier(0); }while(0)

#define NBLK 320

DEV unsigned short f2b(float f){
  unsigned int u = __builtin_bit_cast(unsigned int, f);
  unsigned int r = (u + 0x7FFFu + ((u >> 16) & 1u)) >> 16;
  return (unsigned short)r;
}
DEV float b2f(unsigned short s){
  unsigned int u = ((unsigned int)s) << 16;
  return __builtin_bit_cast(float, u);
}
DEV float tanh_fast(float x){
  const float e = __expf(2.f * x);
  return 1.f - 2.f * __builtin_amdgcn_rcpf(e + 1.f);
}
DEV float sigmoid_fast(float x){
  return __builtin_amdgcn_rcpf(1.f + __expf(-x));
}
DEV void post_u64(unsigned long long* p, unsigned long long v){
  ST2_SC0(p, v);                                   // L2 (same-XCD consumers)
  __hip_atomic_store(p, v, __ATOMIC_RELAXED, __HIP_MEMORY_SCOPE_AGENT); // MALL mirror
}

// ---------------- Phase 0: conversion ----------------
__global__ __launch_bounds__(256) void conv_bf16(const float* __restrict__ src,
                                                 unsigned short* __restrict__ dst,
                                                 int n4){
  int i = blockIdx.x * 256 + threadIdx.x;
  if (i >= n4) return;
  f32x4 v = ((const f32x4*)src)[i];
  u16x4 o;
  #pragma unroll
  for (int j = 0; j < 4; ++j) o[j] = f2b(v[j]);
  ((u16x4*)dst)[i] = o;
}

// h(0): tagged u64 format, tag=0, 2 bf16 cols per u64 in slots [smp][0..255]
__global__ __launch_bounds__(256) void init_h(const float* __restrict__ hx,
                                              unsigned long long* __restrict__ hbuf){
  int s = blockIdx.x;        // 0..63
  int p = threadIdx.x;       // 0..255
  float h0 = hx[s * 512 + 2 * p];
  float h1 = hx[s * 512 + 2 * p + 1];
  unsigned long long v = (unsigned long long)f2b(h0) |
                         ((unsigned long long)f2b(h1) << 16);
  hbuf[(size_t)s * 512 + p] = v;
}

// ---------------- Phase 1: Gpre = Xb @ Wib^T ----------------
__global__ __launch_bounds__(256, 2) void gemm_gi(const unsigned short* __restrict__ Xb,
                                                  const unsigned short* __restrict__ Wib,
                                                  unsigned short* __restrict__ Gp){
  __shared__ unsigned short As[128 * 48];
  __shared__ unsigned short Bs[128 * 48];
  const int tid = threadIdx.x;
  const int m0 = blockIdx.x * 128;
  const int n0 = blockIdx.y * 128;
  const int w = tid >> 6, lane = tid & 63;
  const int lr = lane & 15, lq = lane >> 4;
  const int wm = (w & 1) * 64, wn = (w >> 1) * 64;
  const int sr = tid >> 2;
  const int sc = (tid & 3) * 8;
  const unsigned short* gx = Xb + (size_t)(m0 + sr) * 512 + sc;
  const unsigned short* gw = Wib + (size_t)(n0 + sr) * 512 + sc;
  f32x4 acc[4][4] = {};
  for (int kb = 0; kb < 16; ++kb){
    u32x4 a0 = *(const u32x4*)(gx + kb * 32);
    u32x4 a1 = *(const u32x4*)(gx + 64 * 512 + kb * 32);
    u32x4 b0 = *(const u32x4*)(gw + kb * 32);
    u32x4 b1 = *(const u32x4*)(gw + 64 * 512 + kb * 32);
    __syncthreads();
    *(u32x4*)&As[sr * 48 + sc] = a0;
    *(u32x4*)&As[(sr + 64) * 48 + sc] = a1;
    *(u32x4*)&Bs[sr * 48 + sc] = b0;
    *(u32x4*)&Bs[(sr + 64) * 48 + sc] = b1;
    __syncthreads();
    bf16x8 af[4], bfv[4];
    #pragma unroll
    for (int mi = 0; mi < 4; ++mi) af[mi] = *(const bf16x8*)&As[(wm + mi * 16 + lr) * 48 + lq * 8];
    #pragma unroll
    for (int ni = 0; ni < 4; ++ni) bfv[ni] = *(const bf16x8*)&Bs[(wn + ni * 16 + lr) * 48 + lq * 8];
    #pragma unroll
    for (int mi = 0; mi < 4; ++mi)
      #pragma unroll
      for (int ni = 0; ni < 4; ++ni)
        acc[mi][ni] = __builtin_amdgcn_mfma_f32_16x16x32_bf16(af[mi], bfv[ni], acc[mi][ni], 0, 0, 0);
  }
  #pragma unroll
  for (int mi = 0; mi < 4; ++mi){
    const int rowb = m0 + wm + mi * 16 + lq * 4;
    #pragma unroll
    for (int ni = 0; ni < 4; ++ni){
      const int col = n0 + wn + ni * 16 + lr;
      #pragma unroll
      for (int r = 0; r < 4; ++r)
        Gp[(size_t)(rowb + r) * 2048 + col] = f2b(acc[mi][ni][r]);
    }
  }
}

// ---------------- Phase 1.5: row LN (scale=b1, shift=s1) ----------------
__global__ __launch_bounds__(256) void ln_rows(unsigned short* __restrict__ G,
                                               const float* __restrict__ b1,
                                               const float* __restrict__ s1){
  const int row = blockIdx.x;
  const int tid = threadIdx.x;
  unsigned short* rp = G + (size_t)row * 2048 + tid * 8;
  u32x4 raw = *(const u32x4*)rp;
  float x[8];
  #pragma unroll
  for (int j = 0; j < 8; ++j){
    unsigned int word = raw[j >> 1];
    unsigned short us = (j & 1) ? (unsigned short)(word >> 16) : (unsigned short)(word & 0xFFFF);
    x[j] = b2f(us);
  }
  float s = 0.f, q = 0.f;
  #pragma unroll
  for (int j = 0; j < 8; ++j){ s += x[j]; q += x[j] * x[j]; }
  #pragma unroll
  for (int o = 1; o < 64; o <<= 1){ s += __shfl_xor(s, o); q += __shfl_xor(q, o); }
  __shared__ float ps[4][2];
  const int wv = tid >> 6;
  if ((tid & 63) == 0){ ps[wv][0] = s; ps[wv][1] = q; }
  __syncthreads();
  s = ps[0][0] + ps[1][0] + ps[2][0] + ps[3][0];
  q = ps[0][1] + ps[1][1] + ps[2][1] + ps[3][1];
  const float mu = s * (1.f / 2048.f);
  const float inv = rsqrtf((q - s * mu) + 1e-5f);
  const float* b1p = b1 + tid * 8;
  const float* s1p = s1 + tid * 8;
  u32x4 outw;
  #pragma unroll
  for (int j = 0; j < 4; ++j){
    float y0 = b1p[2 * j]     * ((x[2 * j]     - mu) * inv) + s1p[2 * j];
    float y1 = b1p[2 * j + 1] * ((x[2 * j + 1] - mu) * inv) + s1p[2 * j + 1];
    outw[j] = (unsigned int)f2b(y0) | ((unsigned int)f2b(y1) << 16);
  }
  *(u32x4*)rp = outw;
}

// ---------------- Phase 2: persistent recurrence ----------------
// form[] layout (u32): [0..15] xcd_cnt; [16+x*20+c] grpcnt; [336+x*20+c] teamq;
//                      [656] arrive; [657] team_ctr
__global__ __launch_bounds__(512, 2) void lstm_rec(
    const unsigned short* __restrict__ Gi,   // [32768][2048] bf16, post-LN gi
    const unsigned short* __restrict__ Whb,  // [2048][512] bf16
    const float* __restrict__ bias,
    const float* __restrict__ b2, const float* __restrict__ s2,
    const float* __restrict__ b3, const float* __restrict__ s3,
    const float* __restrict__ cx,
    unsigned long long* __restrict__ hbuf,   // [2][64][512] u64
    unsigned long long* __restrict__ pA,     // [2][4][16][32] tagged u64, zeroed
    unsigned long long* __restrict__ pCs,    // [2][4][16][32] tagged u64, zeroed
    unsigned int* __restrict__ form,         // formation scratch, zeroed
    float* __restrict__ out){
  const int tid = threadIdx.x;

  // ---- runtime team formation: 16 co-located wgs (same XCC) per team ----
  __shared__ int s_tm, s_ks;
  if (tid == 0){
    const unsigned xcd = __builtin_amdgcn_s_getreg((31 << 11) | 20) & 15u; // HW_REG_XCC_ID
    const unsigned k = __hip_atomic_fetch_add(&form[xcd], 1u,
                          __ATOMIC_RELAXED, __HIP_MEMORY_SCOPE_AGENT);
    const unsigned c = k >> 4, m = k & 15u;
    unsigned int* gcnt = &form[16 + xcd * 20 + c];
    unsigned int* tqp  = &form[336 + xcd * 20 + c];
    __hip_atomic_fetch_add(gcnt, 1u, __ATOMIC_RELAXED, __HIP_MEMORY_SCOPE_AGENT);
    __hip_atomic_fetch_add(&form[656], 1u, __ATOMIC_RELEASE, __HIP_MEMORY_SCOPE_AGENT);
    if (m == 0){
      unsigned g;
      for (;;){
        g = __hip_atomic_load(gcnt, __ATOMIC_RELAXED, __HIP_MEMORY_SCOPE_AGENT);
        if (g >= 16u) break;
        unsigned a = __hip_atomic_load(&form[656], __ATOMIC_ACQUIRE, __HIP_MEMORY_SCOPE_AGENT);
        if (a >= (unsigned)NBLK){
          g = __hip_atomic_load(gcnt, __ATOMIC_RELAXED, __HIP_MEMORY_SCOPE_AGENT);
          break;
        }
      }
      unsigned tq = 255u;
      if (g >= 16u)
        tq = __hip_atomic_fetch_add(&form[657], 1u, __ATOMIC_RELAXED, __HIP_MEMORY_SCOPE_AGENT);
      __hip_atomic_store(tqp, tq | 0x100u, __ATOMIC_RELAXED, __HIP_MEMORY_SCOPE_AGENT);
    }
    unsigned v;
    do { v = __hip_atomic_load(tqp, __ATOMIC_RELAXED, __HIP_MEMORY_SCOPE_AGENT); }
    while (!(v & 0x100u));
    s_tm = (int)(v & 0xFFu);
    s_ks = (int)m;
  }
  __syncthreads();
  const int tm = s_tm;
  const int ks = s_ks;
  if (tm >= 4) return;                       // surplus / abandoned wg

  const int w = tid >> 6;
  const int lane = tid & 63;
  const int lr = lane & 15, lq = lane >> 4;

  // gate-wave constants: wave w owns gate rows type*512 + ks*32 + jloc
  const int type = w >> 1;
  const int jloc = (w & 1) * 16 + lr;
  const int row_g = type * 512 + ks * 32 + jloc;
  const float b2r = b2[row_g];
  const float sbr = s2[row_g] + bias[row_g];

  // Wh B-fragments in registers
  bf16x8 bfr[16];
  {
    const unsigned short* wr = Whb + (size_t)row_g * 512 + lq * 8;
    #pragma unroll
    for (int kk = 0; kk < 16; ++kk) bfr[kk] = *(const bf16x8*)(wr + kk * 32);
  }

  // c-phase constants
  const int cs = tid >> 5;                 // team sample 0..15 (== psmp below)
  const int cj = tid & 31;                 // col within slice
  const int hcol = ks * 32 + cj;
  const int bidx = tm * 16 + cs;
  float c_val = cx[(size_t)bidx * 512 + hcol];
  const float b3j = b3[hcol], s3j = s3[hcol];

  // poll coords: wave w covers team samples 2w, 2w+1
  const int psmp = 2 * w + (lane >> 5);    // 0..15 (equals this thread's cs)
  const int pidx = lane & 31;
  const int pl_slice = (lane >> 1) & 15;
  const int pl_kind  = lane & 1;

  // register-cache b3/s3 for the reconstruction cols: c = 2*pidx + 64*jj (+1)
  float b3c[16], s3c[16];
  #pragma unroll
  for (int jj = 0; jj < 8; ++jj){
    const int c0 = 2 * pidx + 64 * jj;
    b3c[2 * jj]     = b3[c0];     b3c[2 * jj + 1] = b3[c0 + 1];
    s3c[2 * jj]     = s3[c0];     s3c[2 * jj + 1] = s3[c0 + 1];
  }

  __shared__ unsigned short hlds[16 * 520];
  __shared__ float act[4][32][17];
  __shared__ float redA[8][16][2];
  __shared__ float stAl[16][2];

  float cc_own = 0.f, o_own = 0.f;
  bool use_mall = false;                   // sticky fallback to MALL loads

  for (int t = 0; t < 512; ++t){
    // gi prefetch (in flight during the merged poll)
    float giv[4];
    #pragma unroll
    for (int r = 0; r < 4; ++r){
      const int b = tm * 16 + lq * 4 + r;
      giv[r] = b2f(Gi[((size_t)b * 512 + t) * 2048 + row_g]);
    }

    if (t == 0){
      // legacy format: (h0,h1) per u64, tag 0, parity 0, slots [smp][0..255]
      const unsigned long long* hsrc = hbuf + (size_t)(tm * 16 + psmp) * 512;
      unsigned long long hv0[8];
      unsigned spin = 0;
      for (;;){
        if (!use_mall){
          #pragma unroll
          for (int j = 0; j < 8; ++j) LD2_SC0(hv0[j], hsrc + pidx + 32 * j);
          VM0_FENCE();
        } else {
          #pragma unroll
          for (int j = 0; j < 8; ++j) LD2_MALL(hv0[j], hsrc + pidx + 32 * j);
        }
        bool ok = true;
        #pragma unroll
        for (int j = 0; j < 8; ++j) ok &= ((unsigned)(hv0[j] >> 32) == 0u);
        if (__all((int)ok)) break;
        if (++spin > 64u) use_mall = true;
      }
      #pragma unroll
      for (int j = 0; j < 8; ++j)
        *(unsigned int*)&hlds[psmp * 520 + 2 * (pidx + 32 * j)] = (unsigned)hv0[j];
    } else {
      // ---- merged rendezvous: (cc,o) per col + c-stats, all tag t ----
      const unsigned int tg = (unsigned)t;
      const unsigned long long* hsrc =
          hbuf + (size_t)(t & 1) * 32768 + (size_t)(tm * 16 + psmp) * 512;
      const unsigned long long* sp =
          pCs + ((size_t)(t & 1) * 4 + tm) * 512 + pl_slice * 32 + psmp * 2 + pl_kind;
      unsigned long long hv[16];
      unsigned long long sv;
      unsigned spin = 0;
      for (;;){
        if (!use_mall){
          #pragma unroll
          for (int j = 0; j < 16; ++j)
            LD2_SC0(hv[j], hsrc + 2 * pidx + 64 * (j >> 1) + (j & 1));
          LD2_SC0(sv, sp);
          VM0_FENCE();
        } else {
          #pragma unroll
          for (int j = 0; j < 16; ++j)
            LD2_MALL(hv[j], hsrc + 2 * pidx + 64 * (j >> 1) + (j & 1));
          LD2_MALL(sv, sp);
        }
        bool ok = true;
        #pragma unroll
        for (int j = 0; j < 16; ++j) ok &= ((unsigned)(hv[j] >> 32) == tg);
        ok &= ((unsigned)(sv >> 32) == tg);
        if (__all((int)ok)) break;
        if (++spin > 64u) use_mall = true;
      }
      // c-stats: butterfly over 16 slices, then kind exchange
      float pv = __builtin_bit_cast(float, (unsigned)sv);
      #pragma unroll
      for (int o = 2; o < 32; o <<= 1) pv += __shfl_xor(pv, o);
      const float ov = __shfl_xor(pv, 1);
      const float S = pl_kind ? ov : pv;
      const float Q = pl_kind ? pv : ov;
      const float mu = S * (1.f / 512.f);
      const float inv = rsqrtf((Q - S * mu) + 1e-5f);
      // own carried state + previous step's out row (sample cs == psmp)
      c_val = b3j * ((cc_own - mu) * inv) + s3j;
      const float h_self = o_own * tanh_fast(c_val);
      out[((size_t)bidx * 512 + (t - 1)) * 512 + hcol] = h_self;
      // reconstruct h(t) for sample psmp: 16 cols per lane
      #pragma unroll
      for (int jj = 0; jj < 8; ++jj){
        const unsigned long long v0 = hv[2 * jj], v1 = hv[2 * jj + 1];
        const float cc0 = b2f((unsigned short)(v0 & 0xFFFF));
        const float oo0 = b2f((unsigned short)((v0 >> 16) & 0xFFFF));
        const float cc1 = b2f((unsigned short)(v1 & 0xFFFF));
        const float oo1 = b2f((unsigned short)((v1 >> 16) & 0xFFFF));
        const float h0 = oo0 * tanh_fast(b3c[2 * jj]     * ((cc0 - mu) * inv) + s3c[2 * jj]);
        const float h1 = oo1 * tanh_fast(b3c[2 * jj + 1] * ((cc1 - mu) * inv) + s3c[2 * jj + 1]);
        *(unsigned int*)&hlds[psmp * 520 + 2 * pidx + 64 * jj] =
            (unsigned)f2b(h0) | ((unsigned)f2b(h1) << 16);
      }
    }
    __syncthreads();                                   // S1

    // A-frags from LDS; MFMA over K=512
    f32x4 acc = {0.f, 0.f, 0.f, 0.f};
    #pragma unroll
    for (int kk = 0; kk < 16; ++kk){
      bf16x8 af = *(const bf16x8*)&hlds[lr * 520 + lq * 8 + kk * 32];
      acc = __builtin_amdgcn_mfma_f32_16x16x32_bf16(af, bfr[kk], acc, 0, 0, 0);
    }
    // per-sample partial (s,q) over this wave's 16 gate cols
    #pragma unroll
    for (int r = 0; r < 4; ++r){
      float s = acc[r], q = acc[r] * acc[r];
      #pragma unroll
      for (int o = 1; o < 16; o <<= 1){ s += __shfl_xor(s, o); q += __shfl_xor(q, o); }
      if (lr == 0){ redA[w][lq * 4 + r][0] = s; redA[w][lq * 4 + r][1] = q; }
    }
    __syncthreads();                                   // S2

    // ---- hop A: tagged partial store + direct all-wave poll ----
    unsigned long long* slotA = pA + ((size_t)(t & 1) * 4 + tm) * 512;  // [16][32] u64
    const unsigned int atag = (unsigned)(t + 1);
    if (w == 0 && lane < 32){
      const int smp = lane >> 1, kd = lane & 1;
      float Sp = 0.f;
      #pragma unroll
      for (int w2 = 0; w2 < 8; ++w2) Sp += redA[w2][smp][kd];
      const unsigned long long pvs = ((unsigned long long)atag << 32) |
          (unsigned long long)__builtin_bit_cast(unsigned int, Sp);
      post_u64(slotA + (size_t)ks * 32 + lane, pvs);
    }
    {
      const unsigned long long* ap = slotA + pl_slice * 32 + psmp * 2 + pl_kind;
      unsigned long long av;
      unsigned spin = 0;
      for (;;){
        if (!use_mall){ LD2_SC0(av, ap); VM0_FENCE(); }
        else          { LD2_MALL(av, ap); }
        if (__all((int)((unsigned)(av >> 32) == atag))) break;
        if (++spin > 64u) use_mall = true;
      }
      float pv = __builtin_bit_cast(float, (unsigned)av);
      #pragma unroll
      for (int o = 2; o < 32; o <<= 1) pv += __shfl_xor(pv, o);  // sum 16 slices
      const float ov = __shfl_xor(pv, 1);
      const float S = pl_kind ? ov : pv;
      const float Q = pl_kind ? pv : ov;
      if ((lane & 31) == 0){
        const float mu = S * (1.f / 2048.f);
        stAl[psmp][0] = mu;
        stAl[psmp][1] = rsqrtf((Q - S * mu) + 1e-5f);
      }
    }
    __syncthreads();                                   // S3

    // gates + activations
    #pragma unroll
    for (int r = 0; r < 4; ++r){
      const int s0 = lq * 4 + r;
      const float nv = (acc[r] - stAl[s0][0]) * stAl[s0][1];
      const float gv = giv[r] + b2r * nv + sbr;
      float a;
      if (type == 2) a = tanh_fast(gv);
      else           a = sigmoid_fast(gv);
      act[type][jloc][s0] = a;
    }
    __syncthreads();                                   // S4

    // c-candidate + per-sample stats (32-lane in-wave reduce)
    const float i_g = act[0][cj][cs];
    const float f_g = act[1][cj][cs];
    const float g_g = act[2][cj][cs];
    const float o_g = act[3][cj][cs];
    const float cc = f_g * c_val + i_g * g_g;
    float sC = cc, qC = cc * cc;
    #pragma unroll
    for (int o = 1; o < 32; o <<= 1){ sC += __shfl_xor(sC, o); qC += __shfl_xor(qC, o); }

    // ---- posts: c-stats + (cc,o) per col, all tag t+1, parity (t+1)&1 ----
    const unsigned int ntag = (unsigned)(t + 1);
    const size_t np = (size_t)((t + 1) & 1);
    unsigned long long* slotC = pCs + (np * 4 + tm) * 512;  // [16][32] u64
    if ((lane & 31) < 2){
      const float v = (lane & 1) ? qC : sC;
      const unsigned long long pvs = ((unsigned long long)ntag << 32) |
          (unsigned long long)__builtin_bit_cast(unsigned int, v);
      post_u64(slotC + (size_t)ks * 32 + cs * 2 + (lane & 1), pvs);
    }
    {
      const unsigned long long pvh = ((unsigned long long)ntag << 32) |
          (unsigned long long)f2b(cc) | ((unsigned long long)f2b(o_g) << 16);
      post_u64(hbuf + np * 32768 + (size_t)bidx * 512 + hcol, pvh);
    }
    cc_own = cc; o_own = o_g;
  }

  // epilogue: finish step-511 LN (tag 512, parity 0) and write tail outputs
  {
    const unsigned long long* sp =
        pCs + ((size_t)0 * 4 + tm) * 512 + pl_slice * 32 + psmp * 2 + pl_kind;
    unsigned long long sv;
    unsigned spin = 0;
    for (;;){
      if (!use_mall){ LD2_SC0(sv, sp); VM0_FENCE(); }
      else          { LD2_MALL(sv, sp); }
      if (__all((int)((unsigned)(sv >> 32) == 512u))) break;
      if (++spin > 64u) use_mall = true;
    }
    float pv = __builtin_bit_cast(float, (unsigned)sv);
    #pragma unroll
    for (int o = 2; o < 32; o <<= 1) pv += __shfl_xor(pv, o);
    const float ov = __shfl_xor(pv, 1);
    const float S = pl_kind ? ov : pv;
    const float Q = pl_kind ? pv : ov;
    const float mu = S * (1.f / 512.f);
    const float inv = rsqrtf((Q - S * mu) + 1e-5f);
    const float cn = b3j * ((cc_own - mu) * inv) + s3j;
    const float h = o_own * tanh_fast(cn);
    out[((size_t)bidx * 512 + 511) * 512 + hcol] = h;
    out[16777216u + (size_t)bidx * 512 + hcol] = h;
    out[16777216u + 32768u + (size_t)bidx * 512 + hcol] = cn;
  }
}

extern "C" void kernel_launch(void* const* d_in, const int* in_sizes, int n_in,
                              void* d_out, int out_size, void* d_ws, size_t ws_size,
                              hipStream_t stream){
  (void)in_sizes; (void)n_in; (void)out_size; (void)ws_size;
  const float* x    = (const float*)d_in[0];
  const float* hx   = (const float*)d_in[1];
  const float* cx   = (const float*)d_in[2];
  const float* Wi   = (const float*)d_in[3];
  const float* Wh   = (const float*)d_in[4];
  const float* bias = (const float*)d_in[5];
  const float* b1   = (const float*)d_in[6];
  const float* b2   = (const float*)d_in[7];
  const float* b3   = (const float*)d_in[8];
  const float* s1   = (const float*)d_in[9];
  const float* s2   = (const float*)d_in[10];
  const float* s3   = (const float*)d_in[11];
  float* out = (float*)d_out;
  char* ws = (char*)d_ws;

  unsigned short*     xb   = (unsigned short*)(ws);                 // 33,554,432
  unsigned short*     wib  = (unsigned short*)(ws + 33554432);      //  2,097,152
  unsigned short*     whb  = (unsigned short*)(ws + 35651584);      //  2,097,152
  unsigned short*     gp   = (unsigned short*)(ws + 37748736);      // 134,217,728
  unsigned long long* hbuf = (unsigned long long*)(ws + 171966464); //    524,288  [2][64][512]
  unsigned long long* pA   = (unsigned long long*)(ws + 172490752); //     32,768
  unsigned long long* pCs  = (unsigned long long*)(ws + 172523520); //     32,768
  unsigned int*       form = (unsigned int*)(ws + 172556288);       //      4,096

  // zero hbuf+pA+pCs+form (contiguous) BEFORE init_h fills hbuf tag-0 slots
  hipMemsetAsync(hbuf, 0, 593920, stream);
  conv_bf16<<<16384, 256, 0, stream>>>(x,  xb,  4194304);
  conv_bf16<<<1024,  256, 0, stream>>>(Wi, wib, 262144);
  conv_bf16<<<1024,  256, 0, stream>>>(Wh, whb, 262144);
  init_h<<<64, 256, 0, stream>>>(hx, hbuf);
  gemm_gi<<<dim3(256, 16, 1), 256, 0, stream>>>(xb, wib, gp);
  ln_rows<<<32768, 256, 0, stream>>>(gp, b1, s1);
  lstm_rec<<<NBLK, 512, 0, stream>>>(gp, whb, bias, b2, s2, b3, s3, cx,
                                     hbuf, pA, pCs, form, out);
}

// Round 4
// 2968.801 us; speedup vs baseline: 1.3913x; 1.3913x over previous
//
#include <hip/hip_runtime.h>
#include <cstdint>
#include <cstddef>

// LayerNormLSTM on MI355X.
// Phase 0: fp32->bf16 conversion of x, Wi, Wh; tagged init of h(0).
// Phase 1: Gpre = x @ Wi^T  (bf16 MFMA 16x16x32, 128x128 tiles).
// Phase 1.5: in-place row LN (scale=b1, shift=s1) over the 2048 gate dim.
// Phase 2: persistent recurrence, 64 wgs = 4 teams(16 samples) x 16 slices.
//   R7 = R5 protocol (2 rendezvous/step, tagged-u64 parity, MALL) with the
//   poll-contention fixes:
//    - hbuf sweep: 8x global_load_dwordx4 sc1 (16B/lane) instead of 16x 8B
//      atomic loads (halves VMEM instructions); sticky >48-spin fallback to
//      the proven per-u64 agent loads (hang-proof).
//    - s_sleep(2) pacing after every failed sweep (cuts sweep rate ~3x).
//    - LDS padded to ~88KB -> 1 wg/CU -> 64 CUs, 8 waves/CU (halves per-CU
//      VMEM/VALU pipe pressure from polling).
//    - h {cc,o} posted BEFORE the c-stat shuffle reduce (chain trim).

typedef float  f32x4 __attribute__((ext_vector_type(4)));
typedef __bf16 bf16x8 __attribute__((ext_vector_type(8)));
typedef unsigned int u32x4 __attribute__((ext_vector_type(4)));
typedef unsigned short u16x4 __attribute__((ext_vector_type(4)));
typedef unsigned long long u64x2 __attribute__((ext_vector_type(2)));

#define DEV __device__ __forceinline__

// agent-scope (MALL) 16B load, untracked by compiler -> manual waitcnt
#define LD4_AGENT(dst, p) asm volatile("global_load_dwordx4 %0, %1, off sc1" : "=v"(dst) : "v"(p))
#define VM0_FENCE() do{ asm volatile("s_waitcnt vmcnt(0)" ::: "memory"); \
                        __builtin_amdgcn_sched_barrier(0); }while(0)

DEV unsigned short f2b(float f){
  unsigned int u = __builtin_bit_cast(unsigned int, f);
  unsigned int r = (u + 0x7FFFu + ((u >> 16) & 1u)) >> 16;
  return (unsigned short)r;
}
DEV float b2f(unsigned short s){
  unsigned int u = ((unsigned int)s) << 16;
  return __builtin_bit_cast(float, u);
}
DEV float tanh_fast(float x){
  const float e = __expf(2.f * x);
  return 1.f - 2.f * __builtin_amdgcn_rcpf(e + 1.f);
}
DEV float sigmoid_fast(float x){
  return __builtin_amdgcn_rcpf(1.f + __expf(-x));
}

// ---------------- Phase 0: conversion ----------------
__global__ __launch_bounds__(256) void conv_bf16(const float* __restrict__ src,
                                                 unsigned short* __restrict__ dst,
                                                 int n4){
  int i = blockIdx.x * 256 + threadIdx.x;
  if (i >= n4) return;
  f32x4 v = ((const f32x4*)src)[i];
  u16x4 o;
  #pragma unroll
  for (int j = 0; j < 4; ++j) o[j] = f2b(v[j]);
  ((u16x4*)dst)[i] = o;
}

// h(0): tagged u64 format, tag=0, 2 bf16 cols per u64 in slots [smp][0..255]
__global__ __launch_bounds__(256) void init_h(const float* __restrict__ hx,
                                              unsigned long long* __restrict__ hbuf){
  int s = blockIdx.x;        // 0..63
  int p = threadIdx.x;       // 0..255
  float h0 = hx[s * 512 + 2 * p];
  float h1 = hx[s * 512 + 2 * p + 1];
  unsigned long long v = (unsigned long long)f2b(h0) |
                         ((unsigned long long)f2b(h1) << 16);
  hbuf[(size_t)s * 512 + p] = v;
}

// ---------------- Phase 1: Gpre = Xb @ Wib^T ----------------
__global__ __launch_bounds__(256, 2) void gemm_gi(const unsigned short* __restrict__ Xb,
                                                  const unsigned short* __restrict__ Wib,
                                                  unsigned short* __restrict__ Gp){
  __shared__ unsigned short As[128 * 48];
  __shared__ unsigned short Bs[128 * 48];
  const int tid = threadIdx.x;
  const int m0 = blockIdx.x * 128;
  const int n0 = blockIdx.y * 128;
  const int w = tid >> 6, lane = tid & 63;
  const int lr = lane & 15, lq = lane >> 4;
  const int wm = (w & 1) * 64, wn = (w >> 1) * 64;
  const int sr = tid >> 2;
  const int sc = (tid & 3) * 8;
  const unsigned short* gx = Xb + (size_t)(m0 + sr) * 512 + sc;
  const unsigned short* gw = Wib + (size_t)(n0 + sr) * 512 + sc;
  f32x4 acc[4][4] = {};
  for (int kb = 0; kb < 16; ++kb){
    u32x4 a0 = *(const u32x4*)(gx + kb * 32);
    u32x4 a1 = *(const u32x4*)(gx + 64 * 512 + kb * 32);
    u32x4 b0 = *(const u32x4*)(gw + kb * 32);
    u32x4 b1 = *(const u32x4*)(gw + 64 * 512 + kb * 32);
    __syncthreads();
    *(u32x4*)&As[sr * 48 + sc] = a0;
    *(u32x4*)&As[(sr + 64) * 48 + sc] = a1;
    *(u32x4*)&Bs[sr * 48 + sc] = b0;
    *(u32x4*)&Bs[(sr + 64) * 48 + sc] = b1;
    __syncthreads();
    bf16x8 af[4], bfv[4];
    #pragma unroll
    for (int mi = 0; mi < 4; ++mi) af[mi] = *(const bf16x8*)&As[(wm + mi * 16 + lr) * 48 + lq * 8];
    #pragma unroll
    for (int ni = 0; ni < 4; ++ni) bfv[ni] = *(const bf16x8*)&Bs[(wn + ni * 16 + lr) * 48 + lq * 8];
    #pragma unroll
    for (int mi = 0; mi < 4; ++mi)
      #pragma unroll
      for (int ni = 0; ni < 4; ++ni)
        acc[mi][ni] = __builtin_amdgcn_mfma_f32_16x16x32_bf16(af[mi], bfv[ni], acc[mi][ni], 0, 0, 0);
  }
  #pragma unroll
  for (int mi = 0; mi < 4; ++mi){
    const int rowb = m0 + wm + mi * 16 + lq * 4;
    #pragma unroll
    for (int ni = 0; ni < 4; ++ni){
      const int col = n0 + wn + ni * 16 + lr;
      #pragma unroll
      for (int r = 0; r < 4; ++r)
        Gp[(size_t)(rowb + r) * 2048 + col] = f2b(acc[mi][ni][r]);
    }
  }
}

// ---------------- Phase 1.5: row LN (scale=b1, shift=s1) ----------------
__global__ __launch_bounds__(256) void ln_rows(unsigned short* __restrict__ G,
                                               const float* __restrict__ b1,
                                               const float* __restrict__ s1){
  const int row = blockIdx.x;
  const int tid = threadIdx.x;
  unsigned short* rp = G + (size_t)row * 2048 + tid * 8;
  u32x4 raw = *(const u32x4*)rp;
  float x[8];
  #pragma unroll
  for (int j = 0; j < 8; ++j){
    unsigned int word = raw[j >> 1];
    unsigned short us = (j & 1) ? (unsigned short)(word >> 16) : (unsigned short)(word & 0xFFFF);
    x[j] = b2f(us);
  }
  float s = 0.f, q = 0.f;
  #pragma unroll
  for (int j = 0; j < 8; ++j){ s += x[j]; q += x[j] * x[j]; }
  #pragma unroll
  for (int o = 1; o < 64; o <<= 1){ s += __shfl_xor(s, o); q += __shfl_xor(q, o); }
  __shared__ float ps[4][2];
  const int wv = tid >> 6;
  if ((tid & 63) == 0){ ps[wv][0] = s; ps[wv][1] = q; }
  __syncthreads();
  s = ps[0][0] + ps[1][0] + ps[2][0] + ps[3][0];
  q = ps[0][1] + ps[1][1] + ps[2][1] + ps[3][1];
  const float mu = s * (1.f / 2048.f);
  const float inv = rsqrtf((q - s * mu) + 1e-5f);
  const float* b1p = b1 + tid * 8;
  const float* s1p = s1 + tid * 8;
  u32x4 outw;
  #pragma unroll
  for (int j = 0; j < 4; ++j){
    float y0 = b1p[2 * j]     * ((x[2 * j]     - mu) * inv) + s1p[2 * j];
    float y1 = b1p[2 * j + 1] * ((x[2 * j + 1] - mu) * inv) + s1p[2 * j + 1];
    outw[j] = (unsigned int)f2b(y0) | ((unsigned int)f2b(y1) << 16);
  }
  *(u32x4*)rp = outw;
}

// ---------------- Phase 2: persistent recurrence ----------------
__global__ __launch_bounds__(512, 2) void lstm_rec(
    const unsigned short* __restrict__ Gi,   // [32768][2048] bf16, post-LN gi
    const unsigned short* __restrict__ Whb,  // [2048][512] bf16
    const float* __restrict__ bias,
    const float* __restrict__ b2, const float* __restrict__ s2,
    const float* __restrict__ b3, const float* __restrict__ s3,
    const float* __restrict__ cx,
    unsigned long long* __restrict__ hbuf,   // [2][64][512] u64
    unsigned long long* __restrict__ pA,     // [2][4][16][32] tagged u64, zeroed
    unsigned long long* __restrict__ pCs,    // [2][4][16][32] tagged u64, zeroed
    float* __restrict__ out){
  const int tid = threadIdx.x;
  const int tm = (blockIdx.x >> 1) & 3;                  // team
  const int ks = ((blockIdx.x >> 3) << 1) | (blockIdx.x & 1);  // slice
  const int w = tid >> 6;
  const int lane = tid & 63;
  const int lr = lane & 15, lq = lane >> 4;

  // gate-wave constants: wave w owns gate rows type*512 + ks*32 + jloc
  const int type = w >> 1;
  const int jloc = (w & 1) * 16 + lr;
  const int row_g = type * 512 + ks * 32 + jloc;
  const float b2r = b2[row_g];
  const float sbr = s2[row_g] + bias[row_g];

  // Wh B-fragments in registers
  bf16x8 bfr[16];
  {
    const unsigned short* wr = Whb + (size_t)row_g * 512 + lq * 8;
    #pragma unroll
    for (int kk = 0; kk < 16; ++kk) bfr[kk] = *(const bf16x8*)(wr + kk * 32);
  }

  // c-phase constants
  const int cs = tid >> 5;                 // team sample 0..15 (== psmp below)
  const int cj = tid & 31;                 // col within slice
  const int hcol = ks * 32 + cj;
  const int bidx = tm * 16 + cs;
  float c_val = cx[(size_t)bidx * 512 + hcol];
  const float b3j = b3[hcol], s3j = s3[hcol];

  // poll coords: wave w covers team samples 2w, 2w+1
  const int psmp = 2 * w + (lane >> 5);    // 0..15 (equals this thread's cs)
  const int pidx = lane & 31;
  const int pl_slice = (lane >> 1) & 15;
  const int pl_kind  = lane & 1;

  // register-cache b3/s3 for the reconstruction cols: c = 2*pidx + 64*jj (+1)
  float b3c[16], s3c[16];
  #pragma unroll
  for (int jj = 0; jj < 8; ++jj){
    const int c0 = 2 * pidx + 64 * jj;
    b3c[2 * jj]     = b3[c0];     b3c[2 * jj + 1] = b3[c0 + 1];
    s3c[2 * jj]     = s3[c0];     s3c[2 * jj + 1] = s3[c0 + 1];
  }

  __shared__ unsigned short hlds[16 * 520];
  __shared__ float act[4][32][17];
  __shared__ float redA[8][16][2];
  __shared__ float stAl[16][2];
  // occupancy limiter: force 1 wg/CU (8 waves/CU) to halve per-CU pipe
  // pressure from polling. Kept alive by an unreachable runtime-guarded use.
  __shared__ char occ_pad[60 * 1024];
  if (blockIdx.x == 0xFFFFu) occ_pad[tid] = (char)tid;

  float cc_own = 0.f, o_own = 0.f;
  bool use_mall = false;                   // sticky fallback to atomic loads

  for (int t = 0; t < 512; ++t){
    // gi prefetch (in flight during the merged poll)
    float giv[4];
    #pragma unroll
    for (int r = 0; r < 4; ++r){
      const int b = tm * 16 + lq * 4 + r;
      giv[r] = b2f(Gi[((size_t)b * 512 + t) * 2048 + row_g]);
    }

    if (t == 0){
      // legacy format: (h0,h1) per u64, tag 0, parity 0, slots [smp][0..255]
      const unsigned long long* hsrc = hbuf + (size_t)(tm * 16 + psmp) * 512;
      unsigned long long hv0[8];
      for (;;){
        bool ok = true;
        #pragma unroll
        for (int j = 0; j < 8; ++j)
          hv0[j] = __hip_atomic_load(hsrc + pidx + 32 * j, __ATOMIC_RELAXED, __HIP_MEMORY_SCOPE_AGENT);
        #pragma unroll
        for (int j = 0; j < 8; ++j) ok &= ((unsigned)(hv0[j] >> 32) == 0u);
        if (__all((int)ok)) break;
        __builtin_amdgcn_s_sleep(2);
      }
      #pragma unroll
      for (int j = 0; j < 8; ++j)
        *(unsigned int*)&hlds[psmp * 520 + 2 * (pidx + 32 * j)] = (unsigned)hv0[j];
    } else {
      // ---- merged rendezvous: (cc,o) per col + c-stats, all tag t ----
      const unsigned int tg = (unsigned)t;
      const unsigned long long* hsrc =
          hbuf + (size_t)(t & 1) * 32768 + (size_t)(tm * 16 + psmp) * 512;
      const unsigned long long* sp =
          pCs + ((size_t)(t & 1) * 4 + tm) * 512 + pl_slice * 32 + psmp * 2 + pl_kind;
      unsigned long long hv[16];
      unsigned long long sv;
      unsigned spin = 0;
      for (;;){
        bool ok = true;
        if (!use_mall){
          u64x2 t4[8];
          #pragma unroll
          for (int q = 0; q < 8; ++q) LD4_AGENT(t4[q], hsrc + 2 * pidx + 64 * q);
          sv = __hip_atomic_load(sp, __ATOMIC_RELAXED, __HIP_MEMORY_SCOPE_AGENT);
          VM0_FENCE();
          #pragma unroll
          for (int q = 0; q < 8; ++q){ hv[2 * q] = t4[q].x; hv[2 * q + 1] = t4[q].y; }
        } else {
          #pragma unroll
          for (int j = 0; j < 16; ++j)
            hv[j] = __hip_atomic_load(hsrc + 2 * pidx + 64 * (j >> 1) + (j & 1),
                                      __ATOMIC_RELAXED, __HIP_MEMORY_SCOPE_AGENT);
          sv = __hip_atomic_load(sp, __ATOMIC_RELAXED, __HIP_MEMORY_SCOPE_AGENT);
        }
        #pragma unroll
        for (int j = 0; j < 16; ++j) ok &= ((unsigned)(hv[j] >> 32) == tg);
        ok &= ((unsigned)(sv >> 32) == tg);
        if (__all((int)ok)) break;
        if (++spin > 48u) use_mall = true;
        __builtin_amdgcn_s_sleep(2);
      }
      // c-stats: butterfly over 16 slices, then kind exchange
      float pv = __builtin_bit_cast(float, (unsigned)sv);
      #pragma unroll
      for (int o = 2; o < 32; o <<= 1) pv += __shfl_xor(pv, o);
      const float ov = __shfl_xor(pv, 1);
      const float S = pl_kind ? ov : pv;
      const float Q = pl_kind ? pv : ov;
      const float mu = S * (1.f / 512.f);
      const float inv = rsqrtf((Q - S * mu) + 1e-5f);
      // own carried state + previous step's out row (sample cs == psmp)
      c_val = b3j * ((cc_own - mu) * inv) + s3j;
      const float h_self = o_own * tanh_fast(c_val);
      out[((size_t)bidx * 512 + (t - 1)) * 512 + hcol] = h_self;
      // reconstruct h(t) for sample psmp: 16 cols per lane
      #pragma unroll
      for (int jj = 0; jj < 8; ++jj){
        const unsigned long long v0 = hv[2 * jj], v1 = hv[2 * jj + 1];
        const float cc0 = b2f((unsigned short)(v0 & 0xFFFF));
        const float oo0 = b2f((unsigned short)((v0 >> 16) & 0xFFFF));
        const float cc1 = b2f((unsigned short)(v1 & 0xFFFF));
        const float oo1 = b2f((unsigned short)((v1 >> 16) & 0xFFFF));
        const float h0 = oo0 * tanh_fast(b3c[2 * jj]     * ((cc0 - mu) * inv) + s3c[2 * jj]);
        const float h1 = oo1 * tanh_fast(b3c[2 * jj + 1] * ((cc1 - mu) * inv) + s3c[2 * jj + 1]);
        *(unsigned int*)&hlds[psmp * 520 + 2 * pidx + 64 * jj] =
            (unsigned)f2b(h0) | ((unsigned)f2b(h1) << 16);
      }
    }
    __syncthreads();                                   // S1

    // A-frags from LDS; MFMA over K=512
    f32x4 acc = {0.f, 0.f, 0.f, 0.f};
    #pragma unroll
    for (int kk = 0; kk < 16; ++kk){
      bf16x8 af = *(const bf16x8*)&hlds[lr * 520 + lq * 8 + kk * 32];
      acc = __builtin_amdgcn_mfma_f32_16x16x32_bf16(af, bfr[kk], acc, 0, 0, 0);
    }
    // per-sample partial (s,q) over this wave's 16 gate cols
    #pragma unroll
    for (int r = 0; r < 4; ++r){
      float s = acc[r], q = acc[r] * acc[r];
      #pragma unroll
      for (int o = 1; o < 16; o <<= 1){ s += __shfl_xor(s, o); q += __shfl_xor(q, o); }
      if (lr == 0){ redA[w][lq * 4 + r][0] = s; redA[w][lq * 4 + r][1] = q; }
    }
    __syncthreads();                                   // S2

    // ---- hop A: tagged partial store + direct all-wave poll ----
    unsigned long long* slotA = pA + ((size_t)(t & 1) * 4 + tm) * 512;  // [16][32] u64
    const unsigned int atag = (unsigned)(t + 1);
    if (w == 0 && lane < 32){
      const int smp = lane >> 1, kd = lane & 1;
      float Sp = 0.f;
      #pragma unroll
      for (int w2 = 0; w2 < 8; ++w2) Sp += redA[w2][smp][kd];
      const unsigned long long pvs = ((unsigned long long)atag << 32) |
          (unsigned long long)__builtin_bit_cast(unsigned int, Sp);
      __hip_atomic_store(slotA + (size_t)ks * 32 + lane, pvs,
                         __ATOMIC_RELAXED, __HIP_MEMORY_SCOPE_AGENT);
    }
    {
      const unsigned long long* ap = slotA + pl_slice * 32 + psmp * 2 + pl_kind;
      unsigned long long av;
      for (;;){
        av = __hip_atomic_load(ap, __ATOMIC_RELAXED, __HIP_MEMORY_SCOPE_AGENT);
        if (__all((int)((unsigned)(av >> 32) == atag))) break;
        __builtin_amdgcn_s_sleep(2);
      }
      float pv = __builtin_bit_cast(float, (unsigned)av);
      #pragma unroll
      for (int o = 2; o < 32; o <<= 1) pv += __shfl_xor(pv, o);  // sum 16 slices
      const float ov = __shfl_xor(pv, 1);
      const float S = pl_kind ? ov : pv;
      const float Q = pl_kind ? pv : ov;
      if ((lane & 31) == 0){
        const float mu = S * (1.f / 2048.f);
        stAl[psmp][0] = mu;
        stAl[psmp][1] = rsqrtf((Q - S * mu) + 1e-5f);
      }
    }
    __syncthreads();                                   // S3

    // gates + activations
    #pragma unroll
    for (int r = 0; r < 4; ++r){
      const int s0 = lq * 4 + r;
      const float nv = (acc[r] - stAl[s0][0]) * stAl[s0][1];
      const float gv = giv[r] + b2r * nv + sbr;
      float a;
      if (type == 2) a = tanh_fast(gv);
      else           a = sigmoid_fast(gv);
      act[type][jloc][s0] = a;
    }
    __syncthreads();                                   // S4

    // c-candidate; post h {cc,o} IMMEDIATELY (before the stat reduce)
    const float i_g = act[0][cj][cs];
    const float f_g = act[1][cj][cs];
    const float g_g = act[2][cj][cs];
    const float o_g = act[3][cj][cs];
    const float cc = f_g * c_val + i_g * g_g;
    const unsigned int ntag = (unsigned)(t + 1);
    const size_t np = (size_t)((t + 1) & 1);
    {
      const unsigned long long pvh = ((unsigned long long)ntag << 32) |
          (unsigned long long)f2b(cc) | ((unsigned long long)f2b(o_g) << 16);
      __hip_atomic_store(hbuf + np * 32768 + (size_t)bidx * 512 + hcol, pvh,
                         __ATOMIC_RELAXED, __HIP_MEMORY_SCOPE_AGENT);
    }
    // per-sample c-stats (32-lane in-wave reduce), then post
    float sC = cc, qC = cc * cc;
    #pragma unroll
    for (int o = 1; o < 32; o <<= 1){ sC += __shfl_xor(sC, o); qC += __shfl_xor(qC, o); }
    unsigned long long* slotC = pCs + (np * 4 + tm) * 512;  // [16][32] u64
    if ((lane & 31) < 2){
      const float v = (lane & 1) ? qC : sC;
      const unsigned long long pvs = ((unsigned long long)ntag << 32) |
          (unsigned long long)__builtin_bit_cast(unsigned int, v);
      __hip_atomic_store(slotC + (size_t)ks * 32 + cs * 2 + (lane & 1), pvs,
                         __ATOMIC_RELAXED, __HIP_MEMORY_SCOPE_AGENT);
    }
    cc_own = cc; o_own = o_g;
  }

  // epilogue: finish step-511 LN (tag 512, parity 0) and write tail outputs
  {
    const unsigned long long* sp =
        pCs + ((size_t)0 * 4 + tm) * 512 + pl_slice * 32 + psmp * 2 + pl_kind;
    unsigned long long sv;
    for (;;){
      sv = __hip_atomic_load(sp, __ATOMIC_RELAXED, __HIP_MEMORY_SCOPE_AGENT);
      if (__all((int)((unsigned)(sv >> 32) == 512u))) break;
      __builtin_amdgcn_s_sleep(2);
    }
    float pv = __builtin_bit_cast(float, (unsigned)sv);
    #pragma unroll
    for (int o = 2; o < 32; o <<= 1) pv += __shfl_xor(pv, o);
    const float ov = __shfl_xor(pv, 1);
    const float S = pl_kind ? ov : pv;
    const float Q = pl_kind ? pv : ov;
    const float mu = S * (1.f / 512.f);
    const float inv = rsqrtf((Q - S * mu) + 1e-5f);
    const float cn = b3j * ((cc_own - mu) * inv) + s3j;
    const float h = o_own * tanh_fast(cn);
    out[((size_t)bidx * 512 + 511) * 512 + hcol] = h;
    out[16777216u + (size_t)bidx * 512 + hcol] = h;
    out[16777216u + 32768u + (size_t)bidx * 512 + hcol] = cn;
  }
}

extern "C" void kernel_launch(void* const* d_in, const int* in_sizes, int n_in,
                              void* d_out, int out_size, void* d_ws, size_t ws_size,
                              hipStream_t stream){
  (void)in_sizes; (void)n_in; (void)out_size; (void)ws_size;
  const float* x    = (const float*)d_in[0];
  const float* hx   = (const float*)d_in[1];
  const float* cx   = (const float*)d_in[2];
  const float* Wi   = (const float*)d_in[3];
  const float* Wh   = (const float*)d_in[4];
  const float* bias = (const float*)d_in[5];
  const float* b1   = (const float*)d_in[6];
  const float* b2   = (const float*)d_in[7];
  const float* b3   = (const float*)d_in[8];
  const float* s1   = (const float*)d_in[9];
  const float* s2   = (const float*)d_in[10];
  const float* s3   = (const float*)d_in[11];
  float* out = (float*)d_out;
  char* ws = (char*)d_ws;

  unsigned short*     xb   = (unsigned short*)(ws);                 // 33,554,432
  unsigned short*     wib  = (unsigned short*)(ws + 33554432);      //  2,097,152
  unsigned short*     whb  = (unsigned short*)(ws + 35651584);      //  2,097,152
  unsigned short*     gp   = (unsigned short*)(ws + 37748736);      // 134,217,728
  unsigned long long* hbuf = (unsigned long long*)(ws + 171966464); //    524,288  [2][64][512]
  unsigned long long* pA   = (unsigned long long*)(ws + 172490752); //     32,768
  unsigned long long* pCs  = (unsigned long long*)(ws + 172523520); //     32,768

  // zero hbuf+pA+pCs (contiguous 589,824 B) BEFORE init_h fills hbuf tag-0 slots
  hipMemsetAsync(hbuf, 0, 589824, stream);
  conv_bf16<<<16384, 256, 0, stream>>>(x,  xb,  4194304);
  conv_bf16<<<1024,  256, 0, stream>>>(Wi, wib, 262144);
  conv_bf16<<<1024,  256, 0, stream>>>(Wh, whb, 262144);
  init_h<<<64, 256, 0, stream>>>(hx, hbuf);
  gemm_gi<<<dim3(256, 16, 1), 256, 0, stream>>>(xb, wib, gp);
  ln_rows<<<32768, 256, 0, stream>>>(gp, b1, s1);
  lstm_rec<<<64, 512, 0, stream>>>(gp, whb, bias, b2, s2, b3, s3, cx,
                                   hbuf, pA, pCs, out);
}